// Round 5
// baseline (562.102 us; speedup 1.0000x reference)
//
#include <hip/hip_runtime.h>

// MPLayer: y[b,v] += p[r]*x[b,u]; y[b,u] += p[r]*x[b,v]  per edge (u,v), relation r.
// R=64, E=100000, N=1000000, B=4.
//
// R5: counting sort of the 12.8M directed messages by cell = (dst bucket [489] x
// src window [4]).  Bin pass stages records in LDS (block-locally sorted) and
// flushes coalesced to exact precomputed global bases (deterministic layout,
// no global atomics).  Accum: one block per dst bucket, LDS accumulate
// (ds_add_f32), records arrive grouped by 4MB src window -> L2-local gathers.

constexpr int  R_   = 64;
constexpr long E_   = 100000;
constexpr int  N_   = 1000000;
constexpr long RE_  = (long)R_ * E_;               // 6.4M edges
constexpr long M2_  = 2 * RE_;                     // 12.8M records
constexpr int  BSH  = 11;
constexpr int  BUCKET = 1 << BSH;                  // 2048 entities / dst bucket
constexpr int  NB   = (N_ + BUCKET - 1) >> BSH;    // 489 dst buckets
constexpr int  WSH  = 18;                          // src window = 262144 entities (4MB xT)
constexpr int  W_   = 4;                           // (1e6-1)>>18 = 3 -> 4 windows
constexpr int  NCELL = NB * W_;                    // 1956 cells
constexpr int  EPB  = 8192;                        // edges per bin/hist block
constexpr int  HB   = (int)((RE_ + EPB - 1) / EPB);// 782 blocks
constexpr int  RPB  = 2 * EPB;                     // 16384 records per bin block

// --- transpose x [4][N] -> xT [N][4] ---
__global__ __launch_bounds__(256) void k_transpose_x(const float* __restrict__ x,
                                                     float4* __restrict__ xT) {
    int i = blockIdx.x * blockDim.x + threadIdx.x;
    if (i < N_) {
        float4 v;
        v.x = x[i];
        v.y = x[(long)N_ + i];
        v.z = x[2L * N_ + i];
        v.w = x[3L * N_ + i];
        xT[i] = v;
    }
}

// --- pass 1: per-(block, cell) histogram, written coalesced ---
__global__ __launch_bounds__(256) void k_hist(const int2* __restrict__ edges,
                                              int* __restrict__ g_bcnt) {
    __shared__ int lc[NCELL];
    for (int i = threadIdx.x; i < NCELL; i += 256) lc[i] = 0;
    __syncthreads();
    long k0 = (long)blockIdx.x * EPB;
    int lim = (int)min((long)EPB, RE_ - k0);
    for (int i = threadIdx.x; i < lim; i += 256) {
        int2 e = edges[k0 + i];
        atomicAdd(&lc[((e.y >> BSH) << 2) | (e.x >> WSH)], 1);
        atomicAdd(&lc[((e.x >> BSH) << 2) | (e.y >> WSH)], 1);
    }
    __syncthreads();
    int* row = g_bcnt + (size_t)blockIdx.x * NCELL;
    for (int i = threadIdx.x; i < NCELL; i += 256) row[i] = lc[i];
}

// --- pass 2a: per-cell totals (columns of g_bcnt, coalesced reads) ---
__global__ __launch_bounds__(1024) void k_colsum(const int* __restrict__ g_bcnt,
                                                 int* __restrict__ ctot) {
    int c = blockIdx.x * 1024 + threadIdx.x;
    if (c < NCELL) {
        int s = 0;
        for (int b = 0; b < HB; ++b) s += g_bcnt[(size_t)b * NCELL + c];
        ctot[c] = s;
    }
}

// --- pass 2b: exclusive scan of 1956 cell totals (1 block) ---
__global__ __launch_bounds__(1024) void k_scan(const int* __restrict__ ctot,
                                               int* __restrict__ cbase) {
    __shared__ int bufA[2048], bufB[2048];
    int t = threadIdx.x;
    for (int i = t; i < 2048; i += 1024) bufA[i] = (i < NCELL) ? ctot[i] : 0;
    __syncthreads();
    int* A = bufA; int* B = bufB;
    for (int off = 1; off < 2048; off <<= 1) {
        for (int i = t; i < 2048; i += 1024) {
            int v = A[i];
            if (i >= off) v += A[i - off];
            B[i] = v;
        }
        __syncthreads();
        int* x = A; A = B; B = x;
    }
    // A = inclusive prefix
    for (int i = t; i < 2048; i += 1024)
        if (i < NCELL) cbase[i] = i ? A[i - 1] : 0;
    if (t == 0) cbase[NCELL] = A[NCELL - 1];
}

// --- pass 2c: expand to per-(block, cell) bases ---
__global__ __launch_bounds__(1024) void k_expand(const int* __restrict__ g_bcnt,
                                                 const int* __restrict__ cbase,
                                                 int* __restrict__ g_bbase) {
    int c = blockIdx.x * 1024 + threadIdx.x;
    if (c < NCELL) {
        int run = cbase[c];
        for (int b = 0; b < HB; ++b) {
            size_t idx = (size_t)b * NCELL + c;
            g_bbase[idx] = run;
            run += g_bcnt[idx];
        }
    }
}

// --- pass 3: LDS-staged local counting sort, coalesced record flush ---
__global__ __launch_bounds__(1024) void k_bin(const int2* __restrict__ edges,
                                              const int* __restrict__ g_bcnt,
                                              const int* __restrict__ g_bbase,
                                              uint2* __restrict__ g_rec) {
    __shared__ uint2 recs[RPB];        // 128 KB
    __shared__ int sA[NCELL];          // counts -> scan ping
    __shared__ int sB[NCELL];          // scan pong -> cursor/ends
    __shared__ int gb[NCELL];          // global bases for this block
    const int t = threadIdx.x;
    const size_t row = (size_t)blockIdx.x * NCELL;
    for (int i = t; i < NCELL; i += 1024) {
        sA[i] = g_bcnt[row + i];
        gb[i] = g_bbase[row + i];
    }
    __syncthreads();
    int* A = sA; int* B = sB;
    for (int off = 1; off < NCELL; off <<= 1) {
        for (int i = t; i < NCELL; i += 1024) {
            int v = A[i];
            if (i >= off) v += A[i - off];
            B[i] = v;
        }
        __syncthreads();
        int* x = A; A = B; B = x;
    }
    int* cur = B;                       // exclusive prefix -> staging cursor
    for (int i = t; i < NCELL; i += 1024) cur[i] = i ? A[i - 1] : 0;
    __syncthreads();

    long k0 = (long)blockIdx.x * EPB;
    int lim = (int)min((long)EPB, RE_ - k0);
    for (int j = 0; j < EPB / 1024; ++j) {
        int i = j * 1024 + t;
        if (i < lim) {
            int2 e = edges[k0 + i];
            unsigned r = (unsigned)(k0 + i) / (unsigned)E_;
            int c1 = ((e.y >> BSH) << 2) | (e.x >> WSH);
            int s1 = atomicAdd(&cur[c1], 1);
            recs[s1] = make_uint2((unsigned)e.y | (r << 20), (unsigned)e.x);
            int c2 = ((e.x >> BSH) << 2) | (e.y >> WSH);
            int s2 = atomicAdd(&cur[c2], 1);
            recs[s2] = make_uint2((unsigned)e.x | (r << 20), (unsigned)e.y);
        }
    }
    __syncthreads();
    // cur[c] is now the END of cell c's local segment (cumulative) -> flush
    int total = 2 * lim;
    for (int s = t; s < total; s += 1024) {
        int lo = 0, hi = NCELL - 1;
        while (lo < hi) { int mid = (lo + hi) >> 1; if (cur[mid] > s) hi = mid; else lo = mid + 1; }
        int start = lo ? cur[lo - 1] : 0;
        g_rec[gb[lo] + (s - start)] = recs[s];
    }
}

// --- pass 4: one block per dst bucket; records arrive grouped by src window ---
__global__ __launch_bounds__(1024) void k_accum(const uint2* __restrict__ g_rec,
                                                const int* __restrict__ cbase,
                                                const float* __restrict__ p,
                                                const float4* __restrict__ xT,
                                                float* __restrict__ y) {
    __shared__ float acc[BUCKET * 4];  // AoS [2048][4]: msg's 4 adds hit 4 banks
    __shared__ float pl[R_];
    int b = blockIdx.x, t = threadIdx.x;
    for (int i = t; i < BUCKET * 4; i += 1024) acc[i] = 0.f;
    if (t < R_) pl[t] = p[t];
    __syncthreads();
    int s0 = cbase[b * W_], cnt = cbase[(b + 1) * W_] - s0;
    int base_e = b << BSH;
    for (int i = 2 * t; i < cnt; i += 2048) {          // 2-record ILP
        uint2 ra = g_rec[s0 + i];
        bool has2 = (i + 1) < cnt;
        uint2 rb = has2 ? g_rec[s0 + i + 1] : ra;
        float  wa = pl[ra.x >> 20];
        float4 xa = xT[ra.y];
        float  wb = pl[rb.x >> 20];
        float4 xb = xT[rb.y];
        int da = ((int)(ra.x & 0xFFFFFu) - base_e) * 4;
        atomicAdd(&acc[da + 0], wa * xa.x);
        atomicAdd(&acc[da + 1], wa * xa.y);
        atomicAdd(&acc[da + 2], wa * xa.z);
        atomicAdd(&acc[da + 3], wa * xa.w);
        if (has2) {
            int db = ((int)(rb.x & 0xFFFFFu) - base_e) * 4;
            atomicAdd(&acc[db + 0], wb * xb.x);
            atomicAdd(&acc[db + 1], wb * xb.y);
            atomicAdd(&acc[db + 2], wb * xb.z);
            atomicAdd(&acc[db + 3], wb * xb.w);
        }
    }
    __syncthreads();
    for (int j = t; j < BUCKET; j += 1024) {
        int i = base_e + j;
        if (i < N_) {
            y[i]            = acc[j * 4 + 0];
            y[(long)N_ + i] = acc[j * 4 + 1];
            y[2L * N_ + i]  = acc[j * 4 + 2];
            y[3L * N_ + i]  = acc[j * 4 + 3];
        }
    }
}

// ---------- fallbacks ----------
__global__ __launch_bounds__(256) void k_scatter_T2(const int2* __restrict__ edges,
                                                    const float* __restrict__ p,
                                                    const float* __restrict__ xT,
                                                    float* __restrict__ yT) {
    const long total  = M2_ * 4;
    const long stride = (long)gridDim.x * blockDim.x;
    for (long t = (long)blockIdx.x * blockDim.x + threadIdx.x; t < total; t += stride) {
        long m = t >> 2;
        int  c = (int)(t & 3);
        long mm = (m >= RE_) ? (m - RE_) : m;
        int2 e = edges[mm];
        int s, d;
        if (m >= RE_) { s = e.y; d = e.x; } else { s = e.x; d = e.y; }
        float w   = p[(int)(mm / E_)];
        float val = w * xT[4L * s + c];
        atomicAdd(&yT[4L * d + c], val);
    }
}

__global__ __launch_bounds__(256) void k_transpose_y(const float4* __restrict__ yT,
                                                     float* __restrict__ y) {
    int i = blockIdx.x * blockDim.x + threadIdx.x;
    if (i < N_) {
        float4 v = yT[i];
        y[i]            = v.x;
        y[(long)N_ + i] = v.y;
        y[2L * N_ + i]  = v.z;
        y[3L * N_ + i]  = v.w;
    }
}

__global__ __launch_bounds__(256) void k_scatter_direct(const int2* __restrict__ edges,
                                                        const float* __restrict__ p,
                                                        const float* __restrict__ x,
                                                        float* __restrict__ y) {
    const long stride = (long)gridDim.x * blockDim.x;
    for (long k = (long)blockIdx.x * blockDim.x + threadIdx.x; k < RE_; k += stride) {
        int2 e = edges[k];
        float w = p[(int)(k / E_)];
        #pragma unroll
        for (int b = 0; b < 4; ++b) {
            float xu = x[(long)b * N_ + e.x];
            float xv = x[(long)b * N_ + e.y];
            atomicAdd(&y[(long)b * N_ + e.y], w * xu);
            atomicAdd(&y[(long)b * N_ + e.x], w * xv);
        }
    }
}

extern "C" void kernel_launch(void* const* d_in, const int* in_sizes, int n_in,
                              void* d_out, int out_size, void* d_ws, size_t ws_size,
                              hipStream_t stream) {
    const float* p     = (const float*)d_in[0];
    const int*   edges = (const int*)d_in[1];
    const float* x     = (const float*)d_in[2];
    float*       y     = (float*)d_out;

    const size_t xT_bytes    = (size_t)N_ * 16;               // 16.0 MB
    const size_t rec_bytes   = (size_t)M2_ * 8;               // 102.4 MB
    const size_t bcnt_bytes  = (size_t)HB * NCELL * 4;        // 6.12 MB
    const size_t ctot_bytes  = (size_t)NCELL * 4;
    const size_t cbase_bytes = (size_t)(NCELL + 1) * 4;
    const size_t need = xT_bytes + rec_bytes + 2 * bcnt_bytes + ctot_bytes + cbase_bytes;

    if (ws_size >= need) {
        char* ws = (char*)d_ws;
        float4* xT      = (float4*)ws;            ws += xT_bytes;
        uint2*  g_rec   = (uint2*)ws;             ws += rec_bytes;
        int*    g_bcnt  = (int*)ws;               ws += bcnt_bytes;
        int*    g_bbase = (int*)ws;               ws += bcnt_bytes;
        int*    ctot    = (int*)ws;               ws += ctot_bytes;
        int*    cbase   = (int*)ws;

        k_transpose_x<<<(N_ + 255) / 256, 256, 0, stream>>>(x, xT);
        k_hist<<<HB, 256, 0, stream>>>((const int2*)edges, g_bcnt);
        k_colsum<<<(NCELL + 1023) / 1024, 1024, 0, stream>>>(g_bcnt, ctot);
        k_scan<<<1, 1024, 0, stream>>>(ctot, cbase);
        k_expand<<<(NCELL + 1023) / 1024, 1024, 0, stream>>>(g_bcnt, cbase, g_bbase);
        k_bin<<<HB, 1024, 0, stream>>>((const int2*)edges, g_bcnt, g_bbase, g_rec);
        k_accum<<<NB, 1024, 0, stream>>>((const uint2*)g_rec, cbase, p,
                                         (const float4*)xT, y);
    } else if (ws_size >= 2 * xT_bytes) {
        float4* xT = (float4*)d_ws;
        float*  yT = (float*)((char*)d_ws + xT_bytes);
        hipMemsetAsync(yT, 0, xT_bytes, stream);
        k_transpose_x<<<(N_ + 255) / 256, 256, 0, stream>>>(x, xT);
        k_scatter_T2<<<16384, 256, 0, stream>>>((const int2*)edges, p,
                                                (const float*)xT, yT);
        k_transpose_y<<<(N_ + 255) / 256, 256, 0, stream>>>((const float4*)yT, y);
    } else {
        hipMemsetAsync(y, 0, (size_t)out_size * sizeof(float), stream);
        k_scatter_direct<<<8192, 256, 0, stream>>>((const int2*)edges, p, x, y);
    }
}